// Round 3
// baseline (179.758 us; speedup 1.0000x reference)
//
#include <hip/hip_runtime.h>
#include <cstddef>
#include <cstdint>

// z: (8, 256, 16,16,16) fp32; embedding: (1024, 256) fp32
#define CDIM 256
#define SPAT 4096
#define KCODE 1024

#define LOSS_OFF 8388608
#define PERP_OFF 8388609
#define IDX_OFF  8388610

typedef __bf16 bf16x8 __attribute__((ext_vector_type(8)));
typedef float floatx16 __attribute__((ext_vector_type(16)));
typedef unsigned short ushort8 __attribute__((ext_vector_type(8)));

__device__ __forceinline__ unsigned short f2bf_rne(float f) {
    union { float f; uint32_t u; } c; c.f = f;
    uint32_t u = c.u;
    return (unsigned short)((u + 0x7fffu + ((u >> 16) & 1u)) >> 16);
}
__device__ __forceinline__ float bf2f(unsigned short h) {
    union { float f; uint32_t u; } c; c.u = ((uint32_t)h) << 16;
    return c.f;
}

// async global->LDS, 16B per lane; lds dest = uniform base + lane*16 (HW adds)
__device__ __forceinline__ void dma16(const void* g, void* l) {
    __builtin_amdgcn_global_load_lds(
        (const __attribute__((address_space(1))) void*)g,
        (__attribute__((address_space(3))) void*)l, 16, 0, 0);
}

// ---------------------------------------------------------------------------
// Prep: split embedding into bf16 hi/lo in the bank-swizzled stage layout:
//   ushort index = stage*8192 + ks*256 + phys*8 + (c&7)
//   phys = kb ^ (ks & 7),  kb = c>>3 (0..31), ks = code&31, stage = code>>5
// Also enorm (exact R1 reduction order), zero counts/losssum, init pbm=~0.
// ---------------------------------------------------------------------------
__global__ __launch_bounds__(256) void vq_prep(const float* __restrict__ emb,
                                               unsigned short* __restrict__ ehsw,
                                               unsigned short* __restrict__ elsw,
                                               float* __restrict__ enorm,
                                               float* __restrict__ counts,
                                               float* __restrict__ losssum,
                                               unsigned long long* __restrict__ pbm) {
    int tid = threadIdx.x;
    if (blockIdx.x == 0) {
        for (int i = tid; i < KCODE; i += 256) counts[i] = 0.0f;
        if (tid == 0) losssum[0] = 0.0f;
    }
    // per-position packed (dist,code) min-key init: +NaN bits > any real key
    if (tid < 128) pbm[blockIdx.x * 128 + tid] = 0xFFFFFFFFFFFFFFFFull;

    int w = tid >> 6, lane = tid & 63;
    int k = blockIdx.x * 4 + w;
    const float* row = emb + (size_t)k * CDIM;
    float s = 0.0f;
#pragma unroll
    for (int i = 0; i < 4; ++i) {
        float v = row[lane + 64 * i];
        s = fmaf(v, v, s);
    }
#pragma unroll
    for (int m = 32; m > 0; m >>= 1) s += __shfl_xor(s, m, 64);
    if (lane == 0) enorm[k] = s;

    float4 v4 = *(const float4*)(row + lane * 4);
    unsigned short h0 = f2bf_rne(v4.x), h1 = f2bf_rne(v4.y),
                   h2 = f2bf_rne(v4.z), h3 = f2bf_rne(v4.w);
    ushort4 hv = make_ushort4(h0, h1, h2, h3);
    ushort4 lv = make_ushort4(f2bf_rne(v4.x - bf2f(h0)), f2bf_rne(v4.y - bf2f(h1)),
                              f2bf_rne(v4.z - bf2f(h2)), f2bf_rne(v4.w - bf2f(h3)));
    int kb = lane >> 1, cj = (lane & 1) * 4;
    int st = k >> 5, ks = k & 31;
    int phys = kb ^ (ks & 7);
    size_t dst = (size_t)st * 8192 + ks * 256 + phys * 8 + cj;
    *(ushort4*)(ehsw + dst) = hv;
    *(ushort4*)(elsw + dst) = lv;
}

// ---------------------------------------------------------------------------
// Dist: 512 blocks x 256 threads (4 waves). Block = (pos tile p, code half kh):
//   pos = bid>>1 (128 spatial positions), kh = bid&1 (512 codes).
// LDS = 68 KB -> 2 blocks/CU: two INDEPENDENT barrier domains per CU, so one
// block's DMA-drain stall overlaps the other's MFMA (m114 mechanism) — the
// R0-R2 monolith had a single coupled domain and never got this.
// Wave w: cols w*32..+32 (1 acc), frag extraction/MFMA chain bit-identical to
// R2. Result merged across the two kh-blocks via packed-u64 atomicMin:
//   key = bits(d)<<32 | code   (d ~ ||z||^2 ~ 256 > 0 -> IEEE-monotone)
// == exact lexicographic (d, code) min == R2's tie rule. Deterministic.
// ---------------------------------------------------------------------------
__global__ __launch_bounds__(256, 2) void vq_dist(const float* __restrict__ z,
                                                  const unsigned short* __restrict__ ehsw,
                                                  const unsigned short* __restrict__ elsw,
                                                  const float* __restrict__ enorm,
                                                  unsigned long long* __restrict__ pbm) {
    __shared__ __align__(16) unsigned char lds[65536 + 2048 + 512];
    float* zhalf = (float*)lds;                 // phase1 overlay on both dbufs
    float* ens_s = (float*)(lds + 65536);       // 512 f (this kh's enorm)
    float* zzs   = (float*)(lds + 67584);       // 128 f

    const int tid = threadIdx.x;
    const int w = tid >> 6;            // wave id 0..3
    const int lane = tid & 63;
    const int m_ = lane & 31;
    const int g = lane >> 5;
    const int bid = blockIdx.x;
    const int pos = bid >> 1;
    const int kh = bid & 1;
    const int ch = w & 1;              // 32-col offset within the 64-col half
    const int hlf = w >> 1;            // which 64-col half this wave extracts
    const int n0 = pos * 128;
    const int b = n0 >> 12;
    const int sp0 = n0 & 4095;
    const float* zb = z + (size_t)b * CDIM * SPAT + sp0;
    const int stg0 = (bid >> 4) & 15;  // stage stagger (harmless, keep)

    ushort8 zh[16], zl[16];

    // ---- phase 1: two 64-col halves ----
    for (int h = 0; h < 2; ++h) {
        for (int i = tid; i < CDIM * 16; i += 256) {
            int c = i >> 4, seg = i & 15;
            *(float4*)&zhalf[c * 64 + seg * 4] =
                *(const float4*)(zb + (size_t)c * SPAT + h * 64 + seg * 4);
        }
        __syncthreads();
        if (hlf == h) {
            // 2 waves extract this half; each takes its 32-col quarter
#pragma unroll
            for (int kc = 0; kc < 16; ++kc) {
#pragma unroll
                for (int j = 0; j < 8; ++j) {
                    float v = zhalf[(kc * 16 + g * 8 + j) * 64 + ch * 32 + m_];
                    unsigned short hb = f2bf_rne(v);
                    unsigned short lb = f2bf_rne(v - bf2f(hb));
                    zh[kc][j] = hb; zl[kc][j] = lb;
                }
            }
        } else if (w == (h == 0 ? 2 : 0)) {
            // zz per column (R1-exact sequential fmaf order)
            float s = 0.0f;
            for (int c = 0; c < CDIM; ++c) {
                float v = zhalf[c * 64 + lane];
                s = fmaf(v, v, s);
            }
            zzs[h * 64 + lane] = s;
        } else if (h == 0 && w == 3) {
            for (int i = lane; i < 512; i += 64) ens_s[i] = enorm[kh * 512 + i];
        }
        __syncthreads();
    }

    const float zzv = zzs[w * 32 + m_];

    float bs = 3.4e38f;
    int bi_ = 0;

    // wave's DMA role: bufid = w>>1 (0:eh, 1:el), hf = w&1 (8 KB half)
    const int bufid = w >> 1;
    const int hf = w & 1;
    const char* gsrc = (const char*)(bufid ? elsw : ehsw);
    const int gs0 = kh * 16;           // global stage base for this code half

    // ---- stage-0 DMA prologue (staggered stage stg0 -> buf0) ----
    {
        const char* gp = gsrc + ((size_t)(gs0 + stg0) << 14) + (hf << 13) + (lane << 4);
        char* lp = (char*)lds + ((size_t)bufid << 14) + (hf << 13);
#pragma unroll
        for (int j = 0; j < 8; ++j) dma16(gp + j * 1024, lp + j * 1024);
    }

    // ---- main loop: 16 stages, double-buffered (2x32 KB) ----
    for (int s = 0; s < 16; ++s) {
        __syncthreads();   // drains DMA(s); all waves done with buf[(s+1)&1]
        if (s < 15) {
            const int se_n = (s + 1 + stg0) & 15;
            const char* gp = gsrc + ((size_t)(gs0 + se_n) << 14) + (hf << 13) + (lane << 4);
            char* lp = (char*)lds + (((size_t)(s + 1) & 1) << 15) +
                       ((size_t)bufid << 14) + (hf << 13);
#pragma unroll
            for (int j = 0; j < 8; ++j) dma16(gp + j * 1024, lp + j * 1024);
            __builtin_amdgcn_sched_barrier(0);   // keep DMA issue above compute
        }
        const char* EHb = (const char*)lds + (((size_t)s & 1) << 15);
        const char* ELb = EHb + 16384;

        floatx16 a = {0.0f, 0.0f, 0.0f, 0.0f, 0.0f, 0.0f, 0.0f, 0.0f,
                      0.0f, 0.0f, 0.0f, 0.0f, 0.0f, 0.0f, 0.0f, 0.0f};
#pragma unroll
        for (int kc = 0; kc < 16; ++kc) {
            int kb0 = kc * 2 + g;
            int off = m_ * 512 + ((kb0 ^ (m_ & 7)) << 4);
            bf16x8 aeh = *(const bf16x8*)(EHb + off);
            bf16x8 ael = *(const bf16x8*)(ELb + off);
            bf16x8 bh = __builtin_bit_cast(bf16x8, zh[kc]);
            bf16x8 bl = __builtin_bit_cast(bf16x8, zl[kc]);
            a = __builtin_amdgcn_mfma_f32_32x32x16_bf16(aeh, bh, a, 0, 0, 0);
            a = __builtin_amdgcn_mfma_f32_32x32x16_bf16(ael, bh, a, 0, 0, 0);
            a = __builtin_amdgcn_mfma_f32_32x32x16_bf16(aeh, bl, a, 0, 0, 0);
        }

        // epilogue: order-independent lexicographic (d, code) argmin
        const int se = (s + stg0) & 15;
#pragma unroll
        for (int reg = 0; reg < 16; ++reg) {
            int mm = (reg & 3) + 8 * (reg >> 2) + 4 * g;
            int il = se * 32 + mm;
            float en = ens_s[il];
            float d = (zzv + en) - 2.0f * a[reg];
            int code = kh * 512 + il;
            if (d < bs || (d == bs && code < bi_)) { bs = d; bi_ = code; }
        }
    }

    // ---- merge g-halves (disjoint code subsets), tie -> low index ----
    {
        float s2 = __shfl_xor(bs, 32, 64);
        int i2 = __shfl_xor(bi_, 32, 64);
        if (s2 < bs || (s2 == bs && i2 < bi_)) { bs = s2; bi_ = i2; }
    }
    // ---- cross-kh merge via packed atomicMin (exact lexicographic) ----
    if (lane < 32) {
        unsigned long long key =
            ((unsigned long long)__float_as_uint(bs) << 32) | (unsigned int)bi_;
        atomicMin(&pbm[n0 + w * 32 + m_], key);
    }
}

// ---------------------------------------------------------------------------
// Gather: 256 blocks x 256 threads. Reads merged (d,code) keys, writes idx
// and counts, DMA-stages the 128 selected rows into LDS (slot stride 1040 B),
// then the BIT-IDENTICAL R2 gather/loss loop (same per-thread fmaf chains,
// same 4 losssum atomics per block).
// ---------------------------------------------------------------------------
__global__ __launch_bounds__(256) void vq_gather(const float* __restrict__ z,
                                                 const float* __restrict__ emb,
                                                 const unsigned long long* __restrict__ pbm,
                                                 float* __restrict__ counts,
                                                 float* __restrict__ losssum,
                                                 float* __restrict__ out) {
    __shared__ __align__(16) unsigned char lds[128 * 1040 + 512];
    int* bidxs = (int*)(lds + 133120);

    const int tid = threadIdx.x;
    const int w = tid >> 6;
    const int lane = tid & 63;
    const int n0 = blockIdx.x * 128;
    const int b = n0 >> 12;
    const int sp0 = n0 & 4095;
    const float* zb = z + (size_t)b * CDIM * SPAT + sp0;

    if (tid < 128) {
        int ki = (int)(unsigned int)(pbm[n0 + tid] & 0xFFFFFFFFull);
        bidxs[tid] = ki;
        out[IDX_OFF + n0 + tid] = (float)ki;
        atomicAdd(&counts[ki], 1.0f);
    }
    __syncthreads();

    // ---- DMA the 128 selected embedding rows into LDS ----
    // slot(row) = (row&3)*32 + (row>>2); byte offset slot*1040 (16B aligned).
#pragma unroll
    for (int r = 0; r < 32; ++r) {
        int row = w * 32 + r;
        int k = bidxs[row];
        int slot = (row & 3) * 32 + (row >> 2);
        dma16((const char*)emb + ((size_t)k << 10) + (lane << 4),
              (char*)lds + (size_t)slot * 1040);
    }
    __syncthreads();

    // ---- gather z_q, STE output zp + (q - zp), loss ----
    float ls = 0.0f;
    float* outz = out + (size_t)b * CDIM * SPAT + sp0;
    const int col4 = tid & 31;         // this thread's 4 columns
    const int c_0 = tid >> 5;          // starting c, stride 8
    const float* e0 = (const float*)((const char*)lds + (size_t)(0 * 32 + col4) * 1040);
    const float* e1 = (const float*)((const char*)lds + (size_t)(1 * 32 + col4) * 1040);
    const float* e2 = (const float*)((const char*)lds + (size_t)(2 * 32 + col4) * 1040);
    const float* e3 = (const float*)((const char*)lds + (size_t)(3 * 32 + col4) * 1040);
    for (int c = c_0; c < CDIM; c += 8) {
        float4 zp = *(const float4*)(zb + (size_t)c * SPAT + col4 * 4);
        float d0 = e0[c] - zp.x, d1 = e1[c] - zp.y,
              d2 = e2[c] - zp.z, d3 = e3[c] - zp.w;
        float4 o;
        o.x = zp.x + d0; o.y = zp.y + d1; o.z = zp.z + d2; o.w = zp.w + d3;
        ls = fmaf(d0, d0, ls); ls = fmaf(d1, d1, ls);
        ls = fmaf(d2, d2, ls); ls = fmaf(d3, d3, ls);
        *(float4*)(outz + (size_t)c * SPAT + col4 * 4) = o;
    }
#pragma unroll
    for (int m = 32; m > 0; m >>= 1) ls += __shfl_xor(ls, m, 64);
    if (lane == 0) atomicAdd(losssum, ls);
}

// ---------------------------------------------------------------------------
// loss + perplexity
// ---------------------------------------------------------------------------
__global__ __launch_bounds__(256) void vq_finalize(const float* __restrict__ counts,
                                                   const float* __restrict__ losssum,
                                                   float* __restrict__ out) {
    __shared__ float red[256];
    int tid = threadIdx.x;
    float s = 0.0f;
    for (int k = tid; k < KCODE; k += 256) {
        float em = counts[k] * (1.0f / 32768.0f);
        s += em * logf(em + 1e-10f);
    }
    red[tid] = s;
    __syncthreads();
    for (int off = 128; off > 0; off >>= 1) {
        if (tid < off) red[tid] += red[tid + off];
        __syncthreads();
    }
    if (tid == 0) {
        float m = losssum[0] * (1.0f / 8388608.0f);
        out[LOSS_OFF] = m + 0.25f * m;
        out[PERP_OFF] = expf(-red[0]);
    }
}

extern "C" void kernel_launch(void* const* d_in, const int* in_sizes, int n_in,
                              void* d_out, int out_size, void* d_ws, size_t ws_size,
                              hipStream_t stream) {
    const float* z = (const float*)d_in[0];
    const float* emb = (const float*)d_in[1];
    float* out = (float*)d_out;
    // workspace layout (8B-aligned first): pbm | ehsw | elsw | enorm | counts | losssum
    unsigned long long* pbm = (unsigned long long*)d_ws;     // 32768 u64 (256 KB)
    unsigned short* ehsw = (unsigned short*)(pbm + 32768);   // 1024*256 ushort
    unsigned short* elsw = ehsw + (size_t)KCODE * CDIM;      // 1024*256 ushort
    float* enorm = (float*)(elsw + (size_t)KCODE * CDIM);    // 1024 f
    float* counts = enorm + KCODE;                           // 1024 f
    float* losssum = counts + KCODE;                         // 1 f

    vq_prep<<<256, 256, 0, stream>>>(emb, ehsw, elsw, enorm, counts, losssum, pbm);
    vq_dist<<<512, 256, 0, stream>>>(z, ehsw, elsw, enorm, pbm);
    vq_gather<<<256, 256, 0, stream>>>(z, emb, pbm, counts, losssum, out);
    vq_finalize<<<1, 256, 0, stream>>>(counts, losssum, out);
}